// Round 12
// baseline (144.014 us; speedup 1.0000x reference)
//
#include <hip/hip_runtime.h>
#include <math.h>

// Problem constants
#define BB 4
#define SS 4096
#define DD 64
#define HH 16
#define PI_C 3.1415f

// ---------------------------------------------------------------------------
// ws layout (bytes):
//   0        : pkv   fp32 [8][64bh][z*64+x]   8,388,608
//   8388608  : pkvs  fp32 [8][64bh][z*64+x]   8,388,608
//   16777216 : pks   fp32 [8][64bh][128]        262,144   (ksum|kssum)
//   17039360 : kvb   bf16 [64bh][z*64+x]        524,288
//   17563648 : kvsb  bf16                       524,288
//   18087936 : ksums fp32 [64bh][128]            32,768
//   18120704 : wT    bf16 wq|wk|wv|wd x 65536   524,288  (only wq,wd written)
// ---------------------------------------------------------------------------

typedef __attribute__((ext_vector_type(8))) short short8;   // 8 x bf16 frag
typedef __attribute__((ext_vector_type(4))) float f32x4;    // MFMA C/D frag

#define MFMA(a, b, c) __builtin_amdgcn_mfma_f32_16x16x32_bf16(a, b, c, 0, 0, 0)

__device__ __forceinline__ short f2bf(float f) {
    union { float f; unsigned u; } v; v.f = f;
    unsigned r = v.u + 0x7FFFu + ((v.u >> 16) & 1u);   // round-to-nearest-even
    return (short)(r >> 16);
}
__device__ __forceinline__ float bf2f(short s) {
    union { unsigned u; float f; } v;
    v.u = ((unsigned)(unsigned short)s) << 16;
    return v.f;
}
__device__ __forceinline__ short8 cvt8(float4 a, float4 b) {
    short8 r;
    r[0] = f2bf(a.x); r[1] = f2bf(a.y); r[2] = f2bf(a.z); r[3] = f2bf(a.w);
    r[4] = f2bf(b.x); r[5] = f2bf(b.y); r[6] = f2bf(b.z); r[7] = f2bf(b.w);
    return r;
}
__device__ __forceinline__ float elu1(float x) { return x > 0.f ? x + 1.f : __expf(x); }
__device__ __forceinline__ void st4(short* p, short a, short b, short c, short d) {
    union { uint2 u; short s[4]; } x;
    x.s[0] = a; x.s[1] = b; x.s[2] = c; x.s[3] = d;
    *reinterpret_cast<uint2*>(p) = x.u;
}

// ---------------------------------------------------------------------------
// Phase 1 (prep-fused, R11-exact): blocks 0..511 = R2 phase1 body with
// SELF-TRANSPOSED wk/wv; blocks 512..543 = prep riders for wq / dense_w.
__global__ __launch_bounds__(256, 2) void k_phase1y(
    const float* __restrict__ key, const float* __restrict__ value,
    const float* __restrict__ wk_b, const float* __restrict__ wv_b,
    const float* __restrict__ wk_w, const float* __restrict__ wv_w,
    const float* __restrict__ wq_w, const float* __restrict__ wd_w,
    float* __restrict__ pkv, float* __restrict__ pkvs,
    float* __restrict__ pks,
    short* __restrict__ wT)
{
    const int blk = blockIdx.x, t = threadIdx.x;

    __shared__ short kT[2][64 * 72], vT[2][64 * 72], vsT[2][64 * 72];   // [buf][x|z][s]
    __shared__ float ssin[512];
    __shared__ float sbk[64], sbv[64];
    __shared__ float sred[512];

    // ---- prep rider blocks: transpose wq (pb<16) / dense_w (pb>=16) ----
    if (blk >= 512) {
        const int pb = blk - 512;
        const int h = pb & 15;
        const bool isQ = (pb < 16);
        const float* src = isQ ? wq_w : wd_w;
        const int rs = isQ ? 1024 : 64;
        const size_t srcbase = isQ ? (size_t)(h * 64) : (size_t)(h * 4096);
        short* dm = wT + (isQ ? (size_t)0 : (size_t)3 * 65536) + (size_t)h * 4096;
#pragma unroll
        for (int j = 0; j < 4; ++j) {
            int idx = j * 1024 + t * 4;
            int r = idx >> 6, c = idx & 63;
            float4 v = *reinterpret_cast<const float4*>(src + (size_t)r * rs + srcbase + c);
            dm[(c + 0) * 64 + r] = f2bf(v.x);
            dm[(c + 1) * 64 + r] = f2bf(v.y);
            dm[(c + 2) * 64 + r] = f2bf(v.z);
            dm[(c + 3) * 64 + r] = f2bf(v.w);
        }
        return;
    }

    const int chunk = blk & 7, h = (blk >> 3) & 15, b = blk >> 7;
    const int w = t >> 6, l = t & 63;
    const int lane15 = l & 15, q8 = (l >> 4) * 8, q4 = (l >> 4) * 4;

    // prefetch K/V rows for iter 0 (independent of LDS; issue first)
    float4 kf0, kf1, kf2, kf3, vf0, vf1, vf2, vf3;
    {
        const size_t g = ((size_t)b * SS + chunk * 512 + w * 16 + lane15) * 64 + q8;
        kf0 = *reinterpret_cast<const float4*>(key + g);
        kf1 = *reinterpret_cast<const float4*>(key + g + 4);
        kf2 = *reinterpret_cast<const float4*>(key + g + 32);
        kf3 = *reinterpret_cast<const float4*>(key + g + 36);
        vf0 = *reinterpret_cast<const float4*>(value + g);
        vf1 = *reinterpret_cast<const float4*>(value + g + 4);
        vf2 = *reinterpret_cast<const float4*>(value + g + 32);
        vf3 = *reinterpret_cast<const float4*>(value + g + 36);
    }

    // ---- self-transpose wk/wv head h into LDS (aliases kT double-buffer) ----
    short* wkL = &kT[0][0];   // [64][72]
    short* wvL = &kT[1][0];   // [64][72]
    {
        const int r = t >> 2, c0 = (t & 3) * 16;
        const float* pkw = wk_w + (size_t)r * 1024 + h * 64 + c0;
        const float* pvw = wv_w + (size_t)r * 1024 + h * 64 + c0;
#pragma unroll
        for (int q = 0; q < 4; ++q) {
            float4 a = *reinterpret_cast<const float4*>(pkw + q * 4);
            float4 v = *reinterpret_cast<const float4*>(pvw + q * 4);
            wkL[(c0 + q * 4 + 0) * 72 + r] = f2bf(a.x);
            wkL[(c0 + q * 4 + 1) * 72 + r] = f2bf(a.y);
            wkL[(c0 + q * 4 + 2) * 72 + r] = f2bf(a.z);
            wkL[(c0 + q * 4 + 3) * 72 + r] = f2bf(a.w);
            wvL[(c0 + q * 4 + 0) * 72 + r] = f2bf(v.x);
            wvL[(c0 + q * 4 + 1) * 72 + r] = f2bf(v.y);
            wvL[(c0 + q * 4 + 2) * 72 + r] = f2bf(v.z);
            wvL[(c0 + q * 4 + 3) * 72 + r] = f2bf(v.w);
        }
    }
    ssin[t]       = __sinf(PI_C * (float)(chunk * 512 + t)       * (1.f / 4096.f));
    ssin[t + 256] = __sinf(PI_C * (float)(chunk * 512 + t + 256) * (1.f / 4096.f));
    if (t < 64) sbk[t] = wk_b[h * 64 + t];
    else if (t < 128) sbv[t - 64] = wv_b[h * 64 + (t - 64)];
    __syncthreads();   // staged weights + ssin/sbk/sbv visible

    // weight B-frags -> registers (bit-identical to prep-based path)
    short8 bkf[2][4], bvf[2][4];
#pragma unroll
    for (int kss = 0; kss < 2; ++kss)
#pragma unroll
        for (int nt = 0; nt < 4; ++nt) {
            bkf[kss][nt] = *reinterpret_cast<const short8*>(&wkL[(nt * 16 + lane15) * 72 + kss * 32 + q8]);
            bvf[kss][nt] = *reinterpret_cast<const short8*>(&wvL[(nt * 16 + lane15) * 72 + kss * 32 + q8]);
        }
    __syncthreads();   // frags read; kT area free for proj_store

    f32x4 ckv[4], ckvs[4];
#pragma unroll
    for (int i = 0; i < 4; ++i) {
        ckv[i]  = (f32x4){0.f, 0.f, 0.f, 0.f};
        ckvs[i] = (f32x4){0.f, 0.f, 0.f, 0.f};
    }
    float aks = 0.f, akss = 0.f;

    // projection + bias + act + transposed bf16 stores into buffer `buf`
    auto proj_store = [&](int buf, int sbase) {
        f32x4 ckp[4], cvp[4];
#pragma unroll
        for (int i = 0; i < 4; ++i) {
            ckp[i] = (f32x4){0.f, 0.f, 0.f, 0.f};
            cvp[i] = (f32x4){0.f, 0.f, 0.f, 0.f};
        }
        short8 ak0 = cvt8(kf0, kf1), ak1 = cvt8(kf2, kf3);
        short8 av0 = cvt8(vf0, vf1), av1 = cvt8(vf2, vf3);
#pragma unroll
        for (int nt = 0; nt < 4; ++nt) {
            ckp[nt] = MFMA(ak0, bkf[0][nt], ckp[nt]);
            cvp[nt] = MFMA(av0, bvf[0][nt], cvp[nt]);
            ckp[nt] = MFMA(ak1, bkf[1][nt], ckp[nt]);
            cvp[nt] = MFMA(av1, bvf[1][nt], cvp[nt]);
        }
        const int srel = w * 16 + q4;
#pragma unroll
        for (int nt = 0; nt < 4; ++nt) {
            const int x = nt * 16 + lane15;
            const float bk = sbk[x], bv = sbv[x];
            short ek[4], ev[4], es[4];
#pragma unroll
            for (int r = 0; r < 4; ++r) {
                float kk = elu1(ckp[nt][r] + bk);
                float vv = cvp[nt][r] + bv;
                ek[r] = f2bf(kk);
                ev[r] = f2bf(vv);
                es[r] = f2bf(vv * ssin[sbase + srel + r]);
            }
            st4(&kT [buf][x * 72 + srel], ek[0], ek[1], ek[2], ek[3]);
            st4(&vT [buf][x * 72 + srel], ev[0], ev[1], ev[2], ev[3]);
            st4(&vsT[buf][x * 72 + srel], es[0], es[1], es[2], es[3]);
        }
    };

    proj_store(0, 0);          // peeled: tile 0 -> buffer 0
    __syncthreads();           // buffer 0 complete

#pragma unroll 1
    for (int it = 0; it < 8; ++it) {
        const int cur = it & 1;
        // ---- prefetch next tile's K/V rows (global; overlaps everything) ----
        if (it < 7) {
            const size_t g = ((size_t)b * SS + chunk * 512 + (it + 1) * 64 + w * 16 + lane15) * 64 + q8;
            kf0 = *reinterpret_cast<const float4*>(key + g);
            kf1 = *reinterpret_cast<const float4*>(key + g + 4);
            kf2 = *reinterpret_cast<const float4*>(key + g + 32);
            kf3 = *reinterpret_cast<const float4*>(key + g + 36);
            vf0 = *reinterpret_cast<const float4*>(value + g);
            vf1 = *reinterpret_cast<const float4*>(value + g + 4);
            vf2 = *reinterpret_cast<const float4*>(value + g + 32);
            vf3 = *reinterpret_cast<const float4*>(value + g + 36);
        }
        // ---- kv / kvs GEMM from buffer cur, swapped: A=v (m=z), B=k' (n=x) ----
#pragma unroll
        for (int kstep = 0; kstep < 2; ++kstep) {
            const int so = kstep * 32;
            short8 aV  = *reinterpret_cast<const short8*>(&vT [cur][(w * 16 + lane15) * 72 + so + q8]);
            short8 aVS = *reinterpret_cast<const short8*>(&vsT[cur][(w * 16 + lane15) * 72 + so + q8]);
#pragma unroll
            for (int nt = 0; nt < 4; ++nt) {
                short8 bK = *reinterpret_cast<const short8*>(&kT[cur][(nt * 16 + lane15) * 72 + so + q8]);
                ckv[nt]  = MFMA(aV,  bK, ckv[nt]);
                ckvs[nt] = MFMA(aVS, bK, ckvs[nt]);
            }
        }
        // ---- ksum / kssum partials (thread: x = l, s-range [w*16,+16)) ----
        {
            const int sbase = it * 64;
            short8 k0 = *reinterpret_cast<const short8*>(&kT[cur][l * 72 + w * 16]);
            short8 k1 = *reinterpret_cast<const short8*>(&kT[cur][l * 72 + w * 16 + 8]);
#pragma unroll
            for (int e = 0; e < 8; ++e) {
                float fa = bf2f(k0[e]), fb = bf2f(k1[e]);
                aks  += fa + fb;
                akss += fa * ssin[sbase + w * 16 + e] + fb * ssin[sbase + w * 16 + 8 + e];
            }
        }
        // ---- project tile it+1 into the other buffer (same interval) ----
        if (it < 7) proj_store(cur ^ 1, (it + 1) * 64);
        __syncthreads();
    }

    // ---- commit: coalesced non-atomic partial stores ([z][x], x = lane15) ----
    const int bh = b * HH + h;
    const size_t pbase = ((size_t)(chunk * 64) + bh) * 4096;
#pragma unroll
    for (int nt = 0; nt < 4; ++nt) {
        const int x = nt * 16 + lane15;
#pragma unroll
        for (int r = 0; r < 4; ++r) {
            const int z = w * 16 + q4 + r;
            pkv [pbase + z * 64 + x] = ckv[nt][r];
            pkvs[pbase + z * 64 + x] = ckvs[nt][r];
        }
    }
    sred[t] = aks; sred[256 + t] = akss;
    __syncthreads();
    if (t < 64) {
        pks[((size_t)(chunk * 64) + bh) * 128 + t] =
            sred[t] + sred[64 + t] + sred[128 + t] + sred[192 + t];
    } else if (t < 128) {
        int tt = t - 64;
        pks[((size_t)(chunk * 64) + bh) * 128 + t] =
            sred[256 + tt] + sred[320 + tt] + sred[384 + tt] + sred[448 + tt];
    }
}

// ---------------------------------------------------------------------------
// Reduce 8 chunk partials -> bf16 kv/kvs + fp32 ksums (R2-exact).
__global__ __launch_bounds__(256) void k_reduce(
    const float* __restrict__ pkv, const float* __restrict__ pkvs,
    const float* __restrict__ pks,
    short* __restrict__ kvb, short* __restrict__ kvsb,
    float* __restrict__ ksums)
{
    const int blk = blockIdx.x, t = threadIdx.x;
    if (blk < 512) {
        const float* src = (blk < 256) ? pkv : pkvs;
        short* dst = (blk < 256) ? kvb : kvsb;
        const int o4 = (blk & 255) * 256 + t;          // float4 index, 0..65535
        float4 s = make_float4(0.f, 0.f, 0.f, 0.f);
#pragma unroll
        for (int c = 0; c < 8; ++c) {
            float4 v = reinterpret_cast<const float4*>(src + (size_t)c * 262144)[o4];
            s.x += v.x; s.y += v.y; s.z += v.z; s.w += v.w;
        }
        st4(dst + (size_t)o4 * 4, f2bf(s.x), f2bf(s.y), f2bf(s.z), f2bf(s.w));
    } else {
        const int g = (blk - 512) * 256 + t;           // float4 index, 0..2047
        float4 s = make_float4(0.f, 0.f, 0.f, 0.f);
#pragma unroll
        for (int c = 0; c < 8; ++c) {
            float4 v = reinterpret_cast<const float4*>(pks + (size_t)c * 8192)[g];
            s.x += v.x; s.y += v.y; s.z += v.z; s.w += v.w;
        }
        reinterpret_cast<float4*>(ksums)[g] = s;
    }
}

// ---------------------------------------------------------------------------
// Phase 2: R11 body (LDS-ksums) + EARLY FRAGMENT LOADS: all of this head's
// kv1/kv2 + dense-weight fragments are issued at the TOP of the head
// iteration, so their ~200cy L2 latency hides under the Q-projection MFMAs
// and denominator VALU. Loads-only reorder -- MFMA order and arithmetic are
// bit-identical. (~+96 VGPR of fragments; (256,2) allows 256, no spill.)
__global__ __launch_bounds__(256, 2) void k_phase2(
    const float* __restrict__ query, const float* __restrict__ wq_b,
    const short* __restrict__ wqTb,
    const short* __restrict__ kvb, const short* __restrict__ kvsb,
    const float* __restrict__ ksums,
    const short* __restrict__ wdTb, const float* __restrict__ dense_b,
    float* __restrict__ out)
{
    const int st = blockIdx.x, b = blockIdx.y;
    const int s0 = st * 32;
    const int t = threadIdx.x, w = t >> 6, l = t & 63;
    const int lane15 = l & 15, q8 = (l >> 4) * 8, q4 = (l >> 4) * 4;

    // LDS union: compute = sqin[32][72] | per-wave sqp[32][72] | per-wave sO[16][72]
    //            reduce view = per-wave float red[32][68]
    __shared__ __align__(16) char smem[34816];
    __shared__ float scc[32];
    __shared__ __align__(16) float sks[2048];   // ksums slice for batch b
    short* sqin = reinterpret_cast<short*>(smem);                    // [32][72]
    short* sqp  = reinterpret_cast<short*>(smem) + 2304 * (1 + w);   // wave's q' [32][72]
    short* sOw  = reinterpret_cast<short*>(smem) + 2304 * 5 + 1152 * w;  // wave's O [16][72]

    // stage q tile (fp32 -> bf16, s-major): 256 thr x 8 floats = 32x64
    {
        const int row = t >> 3, c8 = (t & 7) * 8;
        const float* qp = query + ((size_t)b * SS + s0 + row) * 64 + c8;
        float4 f0 = *reinterpret_cast<const float4*>(qp);
        float4 f1 = *reinterpret_cast<const float4*>(qp + 4);
        *reinterpret_cast<short8*>(&sqin[row * 72 + c8]) = cvt8(f0, f1);
    }
    // preload this batch's ksums (2048 floats) coalesced
    {
        const float* kb = ksums + (size_t)b * HH * 128;
#pragma unroll
        for (int j = 0; j < 2; ++j) {
            const int o4 = j * 256 + t;     // float4 index, 0..511
            reinterpret_cast<float4*>(sks)[o4] =
                reinterpret_cast<const float4*>(kb)[o4];
        }
    }
    if (t < 32) {
        float p = PI_C * (float)(s0 + t) * (1.f / 4096.f);
        scc[t] = __cosf(p) + __sinf(p);
    }
    f32x4 cd[2][4];
#pragma unroll
    for (int rt = 0; rt < 2; ++rt)
#pragma unroll
        for (int nt = 0; nt < 4; ++nt) cd[rt][nt] = (f32x4){0.f, 0.f, 0.f, 0.f};
    __syncthreads();   // q tile + sks + scc ready (only barrier before epilogue)

    // hoisted head-independent values
    short8 aq[2][2];   // q^T B-frags for the 2 row-tiles
#pragma unroll
    for (int rt = 0; rt < 2; ++rt)
#pragma unroll
        for (int kss = 0; kss < 2; ++kss)
            aq[rt][kss] = *reinterpret_cast<const short8*>(&sqin[(rt * 16 + lane15) * 72 + kss * 32 + q8]);
    const float ccs0 = scc[lane15], ccs1 = scc[16 + lane15];  // cos+sin for s-col
    const int drow = l >> 1, dxh = (l & 1) * 32;              // denominator row / x-half
    const float ccr = scc[drow];

#pragma unroll 1
    for (int i = 0; i < 4; ++i) {
        const int h = (i << 2) | w;
        const size_t bh = (size_t)(b * HH + h);
        const short* wqh = wqTb + (size_t)h * 4096;
        const short* wdh = wdTb + (size_t)h * 4096;
        const short* kv1 = kvb  + bh * 4096;
        const short* kv2 = kvsb + bh * 4096;

        // ---- EARLY: issue ALL of this head's kv + dense frag loads now ----
        short8 kf10[4], kf11[4], kf20[4], kf21[4];
        short8 wdf0[4], wdf1[4];
#pragma unroll
        for (int nt = 0; nt < 4; ++nt) {
            const short* a1 = kv1 + (nt * 16 + lane15) * 64;
            const short* a2 = kv2 + (nt * 16 + lane15) * 64;
            kf10[nt] = *reinterpret_cast<const short8*>(a1 + q8);
            kf11[nt] = *reinterpret_cast<const short8*>(a1 + 32 + q8);
            kf20[nt] = *reinterpret_cast<const short8*>(a2 + q8);
            kf21[nt] = *reinterpret_cast<const short8*>(a2 + 32 + q8);
            wdf0[nt] = *reinterpret_cast<const short8*>(wdh + (nt * 16 + lane15) * 64 + q8);
            wdf1[nt] = *reinterpret_cast<const short8*>(wdh + (nt * 16 + lane15) * 64 + 32 + q8);
        }

        // ---- Q projection, SWAPPED (A=wq^T, B=q^T): lane x=nt*16+q4+r, s=rt*16+lane15 ----
        f32x4 cq[2][4];
#pragma unroll
        for (int rt = 0; rt < 2; ++rt)
#pragma unroll
            for (int nt = 0; nt < 4; ++nt) cq[rt][nt] = (f32x4){0.f, 0.f, 0.f, 0.f};
#pragma unroll
        for (int nt = 0; nt < 4; ++nt) {
            short8 b0 = *reinterpret_cast<const short8*>(wqh + (nt * 16 + lane15) * 64 + q8);
            short8 b1 = *reinterpret_cast<const short8*>(wqh + (nt * 16 + lane15) * 64 + 32 + q8);
            cq[0][nt] = MFMA(b0, aq[0][0], cq[0][nt]);
            cq[1][nt] = MFMA(b0, aq[1][0], cq[1][nt]);
            cq[0][nt] = MFMA(b1, aq[0][1], cq[0][nt]);
            cq[1][nt] = MFMA(b1, aq[1][1], cq[1][nt]);
        }
        // bias + elu, store q' s-major
#pragma unroll
        for (int nt = 0; nt < 4; ++nt) {
            float4 bq = *reinterpret_cast<const float4*>(wq_b + h * 64 + nt * 16 + q4);
#pragma unroll
            for (int rt = 0; rt < 2; ++rt) {
                short e0 = f2bf(elu1(cq[rt][nt][0] + bq.x));
                short e1 = f2bf(elu1(cq[rt][nt][1] + bq.y));
                short e2 = f2bf(elu1(cq[rt][nt][2] + bq.z));
                short e3 = f2bf(elu1(cq[rt][nt][3] + bq.w));
                st4(&sqp[(rt * 16 + lane15) * 72 + nt * 16 + q4], e0, e1, e2, e3);
            }
        }

        // ---- denominator: lane covers row drow, x-half dxh (32 terms; LDS) ----
        float invs0, invs1;
        {
            const float* kp = sks + h * 128 + dxh;
            float4 A[8], Bv[8];
#pragma unroll
            for (int j = 0; j < 8; ++j) {
                A[j]  = *reinterpret_cast<const float4*>(kp + j * 4);
                Bv[j] = *reinterpret_cast<const float4*>(kp + 64 + j * 4);
            }
            short8 qr[4];
#pragma unroll
            for (int e = 0; e < 4; ++e)
                qr[e] = *reinterpret_cast<const short8*>(&sqp[drow * 72 + dxh + e * 8]);
            float dsum = 0.f;
#pragma unroll
            for (int j4 = 0; j4 < 8; ++j4)
#pragma unroll
                for (int e4 = 0; e4 < 4; ++e4)
                    dsum += bf2f(qr[j4 >> 1][(j4 & 1) * 4 + e4]) * (A[j4][e4] + ccr * Bv[j4][e4]);
            dsum += __shfl_xor(dsum, 1);
            float invd = 1.f / (dsum + 1e-5f);
            invs0 = __shfl(invd, lane15 * 2);
            invs1 = __shfl(invd, (16 + lane15) * 2);
        }

        // ---- numerator, SWAPPED (A=kv^T, B=q'^T): frags preloaded above ----
        short8 qf[2][2];
#pragma unroll
        for (int rt = 0; rt < 2; ++rt)
#pragma unroll
            for (int kss = 0; kss < 2; ++kss)
                qf[rt][kss] = *reinterpret_cast<const short8*>(&sqp[(rt * 16 + lane15) * 72 + kss * 32 + q8]);
        f32x4 cv1[2][4], cv2[2][4];
#pragma unroll
        for (int rt = 0; rt < 2; ++rt)
#pragma unroll
            for (int nt = 0; nt < 4; ++nt) {
                cv1[rt][nt] = (f32x4){0.f, 0.f, 0.f, 0.f};
                cv2[rt][nt] = (f32x4){0.f, 0.f, 0.f, 0.f};
            }
#pragma unroll
        for (int nt = 0; nt < 4; ++nt) {
#pragma unroll
            for (int rt = 0; rt < 2; ++rt) {
                cv1[rt][nt] = MFMA(kf10[nt], qf[rt][0], cv1[rt][nt]);
                cv1[rt][nt] = MFMA(kf11[nt], qf[rt][1], cv1[rt][nt]);
                cv2[rt][nt] = MFMA(kf20[nt], qf[rt][0], cv2[rt][nt]);
                cv2[rt][nt] = MFMA(kf21[nt], qf[rt][1], cv2[rt][nt]);
            }
        }

        // ---- per row-tile: combine -> O scratch -> dense GEMM ----
#pragma unroll
        for (int rt = 0; rt < 2; ++rt) {
            const float ccsr = rt ? ccs1 : ccs0;
            const float invr = rt ? invs1 : invs0;
#pragma unroll
            for (int nt = 0; nt < 4; ++nt) {
                short e0 = f2bf((cv1[rt][nt][0] + ccsr * cv2[rt][nt][0]) * invr);
                short e1 = f2bf((cv1[rt][nt][1] + ccsr * cv2[rt][nt][1]) * invr);
                short e2 = f2bf((cv1[rt][nt][2] + ccsr * cv2[rt][nt][2]) * invr);
                short e3 = f2bf((cv1[rt][nt][3] + ccsr * cv2[rt][nt][3]) * invr);
                st4(&sOw[lane15 * 72 + nt * 16 + q4], e0, e1, e2, e3);
            }
            short8 of0 = *reinterpret_cast<const short8*>(&sOw[lane15 * 72 + q8]);
            short8 of1 = *reinterpret_cast<const short8*>(&sOw[lane15 * 72 + 32 + q8]);
#pragma unroll
            for (int nt = 0; nt < 4; ++nt) {
                cd[rt][nt] = MFMA(of0, wdf0[nt], cd[rt][nt]);
                cd[rt][nt] = MFMA(of1, wdf1[nt], cd[rt][nt]);
            }
        }
    }

    // ---- cross-wave reduction of dense partials (re-alias LDS union) ----
    __syncthreads();   // all compute reads of smem done
    {
        float* red = reinterpret_cast<float*>(smem) + 2176 * w;   // [32][68]
#pragma unroll
        for (int rt = 0; rt < 2; ++rt)
#pragma unroll
            for (int nt = 0; nt < 4; ++nt)
#pragma unroll
                for (int r = 0; r < 4; ++r)
                    red[(rt * 16 + q4 + r) * 68 + nt * 16 + lane15] = cd[rt][nt][r];
    }
    __syncthreads();
    {
        const int row = t >> 3, c8 = (t & 7) * 8;
        float4 sa = make_float4(0.f, 0.f, 0.f, 0.f);
        float4 sb = make_float4(0.f, 0.f, 0.f, 0.f);
#pragma unroll
        for (int ww = 0; ww < 4; ++ww) {
            const float* red = reinterpret_cast<const float*>(smem) + 2176 * ww;
            float4 v0 = *reinterpret_cast<const float4*>(red + row * 68 + c8);
            float4 v1 = *reinterpret_cast<const float4*>(red + row * 68 + c8 + 4);
            sa.x += v0.x; sa.y += v0.y; sa.z += v0.z; sa.w += v0.w;
            sb.x += v1.x; sb.y += v1.y; sb.z += v1.z; sb.w += v1.w;
        }
        float4 d0 = *reinterpret_cast<const float4*>(dense_b + c8);
        float4 d1 = *reinterpret_cast<const float4*>(dense_b + c8 + 4);
        sa.x += d0.x; sa.y += d0.y; sa.z += d0.z; sa.w += d0.w;
        sb.x += d1.x; sb.y += d1.y; sb.z += d1.z; sb.w += d1.w;
        float* op = out + ((size_t)b * SS + s0 + row) * 64 + c8;
        *reinterpret_cast<float4*>(op)     = sa;
        *reinterpret_cast<float4*>(op + 4) = sb;
    }
}

// ---------------------------------------------------------------------------
extern "C" void kernel_launch(void* const* d_in, const int* in_sizes, int n_in,
                              void* d_out, int out_size, void* d_ws, size_t ws_size,
                              hipStream_t stream) {
    const float* query   = (const float*)d_in[0];
    const float* key     = (const float*)d_in[1];
    const float* value   = (const float*)d_in[2];
    // d_in[3] attn_mask unused
    const float* wq_w    = (const float*)d_in[4];
    const float* wq_b    = (const float*)d_in[5];
    const float* wk_w    = (const float*)d_in[6];
    const float* wk_b    = (const float*)d_in[7];
    const float* wv_w    = (const float*)d_in[8];
    const float* wv_b    = (const float*)d_in[9];
    const float* dense_w = (const float*)d_in[10];
    const float* dense_b = (const float*)d_in[11];
    float* out = (float*)d_out;

    char* ws = (char*)d_ws;
    float* pkv   = (float*)(ws);
    float* pkvs  = (float*)(ws + 8388608);
    float* pks   = (float*)(ws + 16777216);
    short* kvb   = (short*)(ws + 17039360);
    short* kvsb  = (short*)(ws + 17563648);
    float* ksums = (float*)(ws + 18087936);
    short* wT    = (short*)(ws + 18120704);  // wq|wk|wv|wd, 65536 shorts each
    short* wqTb  = wT;
    short* wdTb  = wT + 196608;

    hipLaunchKernelGGL(k_phase1y, dim3(544), dim3(256), 0, stream,
                       key, value, wk_b, wv_b, wk_w, wv_w, wq_w, dense_w,
                       pkv, pkvs, pks, wT);
    hipLaunchKernelGGL(k_reduce, dim3(520), dim3(256), 0, stream,
                       pkv, pkvs, pks, kvb, kvsb, ksums);
    hipLaunchKernelGGL(k_phase2, dim3(128, BB), dim3(256), 0, stream,
                       query, wq_b, wqTb, kvb, kvsb, ksums, wdTb, dense_b, out);
}

// Round 13
// 141.966 us; speedup vs baseline: 1.0144x; 1.0144x over previous
//
#include <hip/hip_runtime.h>
#include <math.h>

// Problem constants
#define BB 4
#define SS 4096
#define DD 64
#define HH 16
#define PI_C 3.1415f

// ---------------------------------------------------------------------------
// ws layout (bytes):
//   0        : pkv   fp32 [8][64bh][z*64+x]   8,388,608
//   8388608  : pkvs  fp32 [8][64bh][z*64+x]   8,388,608
//   16777216 : pks   fp32 [8][64bh][128]        262,144   (ksum|kssum)
//   17039360 : kvb   bf16 [64bh][z*64+x]        524,288
//   17563648 : kvsb  bf16                       524,288
//   18087936 : ksums fp32 [64bh][128]            32,768
//   18120704 : wT    bf16 wq|wk|wv|wd x 65536   524,288  (only wq,wd written)
// ---------------------------------------------------------------------------

typedef __attribute__((ext_vector_type(8))) short short8;   // 8 x bf16 frag
typedef __attribute__((ext_vector_type(4))) float f32x4;    // MFMA C/D frag

#define MFMA(a, b, c) __builtin_amdgcn_mfma_f32_16x16x32_bf16(a, b, c, 0, 0, 0)

__device__ __forceinline__ short f2bf(float f) {
    union { float f; unsigned u; } v; v.f = f;
    unsigned r = v.u + 0x7FFFu + ((v.u >> 16) & 1u);   // round-to-nearest-even
    return (short)(r >> 16);
}
__device__ __forceinline__ float bf2f(short s) {
    union { unsigned u; float f; } v;
    v.u = ((unsigned)(unsigned short)s) << 16;
    return v.f;
}
__device__ __forceinline__ short8 cvt8(float4 a, float4 b) {
    short8 r;
    r[0] = f2bf(a.x); r[1] = f2bf(a.y); r[2] = f2bf(a.z); r[3] = f2bf(a.w);
    r[4] = f2bf(b.x); r[5] = f2bf(b.y); r[6] = f2bf(b.z); r[7] = f2bf(b.w);
    return r;
}
__device__ __forceinline__ float elu1(float x) { return x > 0.f ? x + 1.f : __expf(x); }
__device__ __forceinline__ void st4(short* p, short a, short b, short c, short d) {
    union { uint2 u; short s[4]; } x;
    x.s[0] = a; x.s[1] = b; x.s[2] = c; x.s[3] = d;
    *reinterpret_cast<uint2*>(p) = x.u;
}

// ---------------------------------------------------------------------------
// Phase 1 (prep-fused, R11-exact): blocks 0..511 = R2 phase1 body with
// SELF-TRANSPOSED wk/wv; blocks 512..543 = prep riders for wq / dense_w.
__global__ __launch_bounds__(256, 2) void k_phase1y(
    const float* __restrict__ key, const float* __restrict__ value,
    const float* __restrict__ wk_b, const float* __restrict__ wv_b,
    const float* __restrict__ wk_w, const float* __restrict__ wv_w,
    const float* __restrict__ wq_w, const float* __restrict__ wd_w,
    float* __restrict__ pkv, float* __restrict__ pkvs,
    float* __restrict__ pks,
    short* __restrict__ wT)
{
    const int blk = blockIdx.x, t = threadIdx.x;

    __shared__ short kT[2][64 * 72], vT[2][64 * 72], vsT[2][64 * 72];   // [buf][x|z][s]
    __shared__ float ssin[512];
    __shared__ float sbk[64], sbv[64];
    __shared__ float sred[512];

    // ---- prep rider blocks: transpose wq (pb<16) / dense_w (pb>=16) ----
    if (blk >= 512) {
        const int pb = blk - 512;
        const int h = pb & 15;
        const bool isQ = (pb < 16);
        const float* src = isQ ? wq_w : wd_w;
        const int rs = isQ ? 1024 : 64;
        const size_t srcbase = isQ ? (size_t)(h * 64) : (size_t)(h * 4096);
        short* dm = wT + (isQ ? (size_t)0 : (size_t)3 * 65536) + (size_t)h * 4096;
#pragma unroll
        for (int j = 0; j < 4; ++j) {
            int idx = j * 1024 + t * 4;
            int r = idx >> 6, c = idx & 63;
            float4 v = *reinterpret_cast<const float4*>(src + (size_t)r * rs + srcbase + c);
            dm[(c + 0) * 64 + r] = f2bf(v.x);
            dm[(c + 1) * 64 + r] = f2bf(v.y);
            dm[(c + 2) * 64 + r] = f2bf(v.z);
            dm[(c + 3) * 64 + r] = f2bf(v.w);
        }
        return;
    }

    const int chunk = blk & 7, h = (blk >> 3) & 15, b = blk >> 7;
    const int w = t >> 6, l = t & 63;
    const int lane15 = l & 15, q8 = (l >> 4) * 8, q4 = (l >> 4) * 4;

    // prefetch K/V rows for iter 0 (independent of LDS; issue first)
    float4 kf0, kf1, kf2, kf3, vf0, vf1, vf2, vf3;
    {
        const size_t g = ((size_t)b * SS + chunk * 512 + w * 16 + lane15) * 64 + q8;
        kf0 = *reinterpret_cast<const float4*>(key + g);
        kf1 = *reinterpret_cast<const float4*>(key + g + 4);
        kf2 = *reinterpret_cast<const float4*>(key + g + 32);
        kf3 = *reinterpret_cast<const float4*>(key + g + 36);
        vf0 = *reinterpret_cast<const float4*>(value + g);
        vf1 = *reinterpret_cast<const float4*>(value + g + 4);
        vf2 = *reinterpret_cast<const float4*>(value + g + 32);
        vf3 = *reinterpret_cast<const float4*>(value + g + 36);
    }

    // ---- self-transpose wk/wv head h into LDS (aliases kT double-buffer) ----
    short* wkL = &kT[0][0];   // [64][72]
    short* wvL = &kT[1][0];   // [64][72]
    {
        const int r = t >> 2, c0 = (t & 3) * 16;
        const float* pkw = wk_w + (size_t)r * 1024 + h * 64 + c0;
        const float* pvw = wv_w + (size_t)r * 1024 + h * 64 + c0;
#pragma unroll
        for (int q = 0; q < 4; ++q) {
            float4 a = *reinterpret_cast<const float4*>(pkw + q * 4);
            float4 v = *reinterpret_cast<const float4*>(pvw + q * 4);
            wkL[(c0 + q * 4 + 0) * 72 + r] = f2bf(a.x);
            wkL[(c0 + q * 4 + 1) * 72 + r] = f2bf(a.y);
            wkL[(c0 + q * 4 + 2) * 72 + r] = f2bf(a.z);
            wkL[(c0 + q * 4 + 3) * 72 + r] = f2bf(a.w);
            wvL[(c0 + q * 4 + 0) * 72 + r] = f2bf(v.x);
            wvL[(c0 + q * 4 + 1) * 72 + r] = f2bf(v.y);
            wvL[(c0 + q * 4 + 2) * 72 + r] = f2bf(v.z);
            wvL[(c0 + q * 4 + 3) * 72 + r] = f2bf(v.w);
        }
    }
    ssin[t]       = __sinf(PI_C * (float)(chunk * 512 + t)       * (1.f / 4096.f));
    ssin[t + 256] = __sinf(PI_C * (float)(chunk * 512 + t + 256) * (1.f / 4096.f));
    if (t < 64) sbk[t] = wk_b[h * 64 + t];
    else if (t < 128) sbv[t - 64] = wv_b[h * 64 + (t - 64)];
    __syncthreads();   // staged weights + ssin/sbk/sbv visible

    // weight B-frags -> registers (bit-identical to prep-based path)
    short8 bkf[2][4], bvf[2][4];
#pragma unroll
    for (int kss = 0; kss < 2; ++kss)
#pragma unroll
        for (int nt = 0; nt < 4; ++nt) {
            bkf[kss][nt] = *reinterpret_cast<const short8*>(&wkL[(nt * 16 + lane15) * 72 + kss * 32 + q8]);
            bvf[kss][nt] = *reinterpret_cast<const short8*>(&wvL[(nt * 16 + lane15) * 72 + kss * 32 + q8]);
        }
    __syncthreads();   // frags read; kT area free for proj_store

    f32x4 ckv[4], ckvs[4];
#pragma unroll
    for (int i = 0; i < 4; ++i) {
        ckv[i]  = (f32x4){0.f, 0.f, 0.f, 0.f};
        ckvs[i] = (f32x4){0.f, 0.f, 0.f, 0.f};
    }
    float aks = 0.f, akss = 0.f;

    // projection + bias + act + transposed bf16 stores into buffer `buf`
    auto proj_store = [&](int buf, int sbase) {
        f32x4 ckp[4], cvp[4];
#pragma unroll
        for (int i = 0; i < 4; ++i) {
            ckp[i] = (f32x4){0.f, 0.f, 0.f, 0.f};
            cvp[i] = (f32x4){0.f, 0.f, 0.f, 0.f};
        }
        short8 ak0 = cvt8(kf0, kf1), ak1 = cvt8(kf2, kf3);
        short8 av0 = cvt8(vf0, vf1), av1 = cvt8(vf2, vf3);
#pragma unroll
        for (int nt = 0; nt < 4; ++nt) {
            ckp[nt] = MFMA(ak0, bkf[0][nt], ckp[nt]);
            cvp[nt] = MFMA(av0, bvf[0][nt], cvp[nt]);
            ckp[nt] = MFMA(ak1, bkf[1][nt], ckp[nt]);
            cvp[nt] = MFMA(av1, bvf[1][nt], cvp[nt]);
        }
        const int srel = w * 16 + q4;
#pragma unroll
        for (int nt = 0; nt < 4; ++nt) {
            const int x = nt * 16 + lane15;
            const float bk = sbk[x], bv = sbv[x];
            short ek[4], ev[4], es[4];
#pragma unroll
            for (int r = 0; r < 4; ++r) {
                float kk = elu1(ckp[nt][r] + bk);
                float vv = cvp[nt][r] + bv;
                ek[r] = f2bf(kk);
                ev[r] = f2bf(vv);
                es[r] = f2bf(vv * ssin[sbase + srel + r]);
            }
            st4(&kT [buf][x * 72 + srel], ek[0], ek[1], ek[2], ek[3]);
            st4(&vT [buf][x * 72 + srel], ev[0], ev[1], ev[2], ev[3]);
            st4(&vsT[buf][x * 72 + srel], es[0], es[1], es[2], es[3]);
        }
    };

    proj_store(0, 0);          // peeled: tile 0 -> buffer 0
    __syncthreads();           // buffer 0 complete

#pragma unroll 1
    for (int it = 0; it < 8; ++it) {
        const int cur = it & 1;
        // ---- prefetch next tile's K/V rows (global; overlaps everything) ----
        if (it < 7) {
            const size_t g = ((size_t)b * SS + chunk * 512 + (it + 1) * 64 + w * 16 + lane15) * 64 + q8;
            kf0 = *reinterpret_cast<const float4*>(key + g);
            kf1 = *reinterpret_cast<const float4*>(key + g + 4);
            kf2 = *reinterpret_cast<const float4*>(key + g + 32);
            kf3 = *reinterpret_cast<const float4*>(key + g + 36);
            vf0 = *reinterpret_cast<const float4*>(value + g);
            vf1 = *reinterpret_cast<const float4*>(value + g + 4);
            vf2 = *reinterpret_cast<const float4*>(value + g + 32);
            vf3 = *reinterpret_cast<const float4*>(value + g + 36);
        }
        // ---- kv / kvs GEMM from buffer cur, swapped: A=v (m=z), B=k' (n=x) ----
#pragma unroll
        for (int kstep = 0; kstep < 2; ++kstep) {
            const int so = kstep * 32;
            short8 aV  = *reinterpret_cast<const short8*>(&vT [cur][(w * 16 + lane15) * 72 + so + q8]);
            short8 aVS = *reinterpret_cast<const short8*>(&vsT[cur][(w * 16 + lane15) * 72 + so + q8]);
#pragma unroll
            for (int nt = 0; nt < 4; ++nt) {
                short8 bK = *reinterpret_cast<const short8*>(&kT[cur][(nt * 16 + lane15) * 72 + so + q8]);
                ckv[nt]  = MFMA(aV,  bK, ckv[nt]);
                ckvs[nt] = MFMA(aVS, bK, ckvs[nt]);
            }
        }
        // ---- ksum / kssum partials (thread: x = l, s-range [w*16,+16)) ----
        {
            const int sbase = it * 64;
            short8 k0 = *reinterpret_cast<const short8*>(&kT[cur][l * 72 + w * 16]);
            short8 k1 = *reinterpret_cast<const short8*>(&kT[cur][l * 72 + w * 16 + 8]);
#pragma unroll
            for (int e = 0; e < 8; ++e) {
                float fa = bf2f(k0[e]), fb = bf2f(k1[e]);
                aks  += fa + fb;
                akss += fa * ssin[sbase + w * 16 + e] + fb * ssin[sbase + w * 16 + 8 + e];
            }
        }
        // ---- project tile it+1 into the other buffer (same interval) ----
        if (it < 7) proj_store(cur ^ 1, (it + 1) * 64);
        __syncthreads();
    }

    // ---- commit: coalesced non-atomic partial stores ([z][x], x = lane15) ----
    const int bh = b * HH + h;
    const size_t pbase = ((size_t)(chunk * 64) + bh) * 4096;
#pragma unroll
    for (int nt = 0; nt < 4; ++nt) {
        const int x = nt * 16 + lane15;
#pragma unroll
        for (int r = 0; r < 4; ++r) {
            const int z = w * 16 + q4 + r;
            pkv [pbase + z * 64 + x] = ckv[nt][r];
            pkvs[pbase + z * 64 + x] = ckvs[nt][r];
        }
    }
    sred[t] = aks; sred[256 + t] = akss;
    __syncthreads();
    if (t < 64) {
        pks[((size_t)(chunk * 64) + bh) * 128 + t] =
            sred[t] + sred[64 + t] + sred[128 + t] + sred[192 + t];
    } else if (t < 128) {
        int tt = t - 64;
        pks[((size_t)(chunk * 64) + bh) * 128 + t] =
            sred[256 + tt] + sred[320 + tt] + sred[384 + tt] + sred[448 + tt];
    }
}

// ---------------------------------------------------------------------------
// Reduce 8 chunk partials -> bf16 kv/kvs + fp32 ksums (R2-exact).
__global__ __launch_bounds__(256) void k_reduce(
    const float* __restrict__ pkv, const float* __restrict__ pkvs,
    const float* __restrict__ pks,
    short* __restrict__ kvb, short* __restrict__ kvsb,
    float* __restrict__ ksums)
{
    const int blk = blockIdx.x, t = threadIdx.x;
    if (blk < 512) {
        const float* src = (blk < 256) ? pkv : pkvs;
        short* dst = (blk < 256) ? kvb : kvsb;
        const int o4 = (blk & 255) * 256 + t;          // float4 index, 0..65535
        float4 s = make_float4(0.f, 0.f, 0.f, 0.f);
#pragma unroll
        for (int c = 0; c < 8; ++c) {
            float4 v = reinterpret_cast<const float4*>(src + (size_t)c * 262144)[o4];
            s.x += v.x; s.y += v.y; s.z += v.z; s.w += v.w;
        }
        st4(dst + (size_t)o4 * 4, f2bf(s.x), f2bf(s.y), f2bf(s.z), f2bf(s.w));
    } else {
        const int g = (blk - 512) * 256 + t;           // float4 index, 0..2047
        float4 s = make_float4(0.f, 0.f, 0.f, 0.f);
#pragma unroll
        for (int c = 0; c < 8; ++c) {
            float4 v = reinterpret_cast<const float4*>(pks + (size_t)c * 8192)[g];
            s.x += v.x; s.y += v.y; s.z += v.z; s.w += v.w;
        }
        reinterpret_cast<float4*>(ksums)[g] = s;
    }
}

// ---------------------------------------------------------------------------
// Phase 2: R12 body with the head loop SOFTWARE-PIPELINED via #pragma unroll 2
// (head i+1's early fragment loads + Q-proj overlap head i's numerator/dense
// MFMAs; reg peak est. ~240-250 unified, under the 256 quantum so occupancy
// stays 8 waves/CU). Per-head arithmetic order unchanged -> bit-exact.
__global__ __launch_bounds__(256, 2) void k_phase2(
    const float* __restrict__ query, const float* __restrict__ wq_b,
    const short* __restrict__ wqTb,
    const short* __restrict__ kvb, const short* __restrict__ kvsb,
    const float* __restrict__ ksums,
    const short* __restrict__ wdTb, const float* __restrict__ dense_b,
    float* __restrict__ out)
{
    const int st = blockIdx.x, b = blockIdx.y;
    const int s0 = st * 32;
    const int t = threadIdx.x, w = t >> 6, l = t & 63;
    const int lane15 = l & 15, q8 = (l >> 4) * 8, q4 = (l >> 4) * 4;

    // LDS union: compute = sqin[32][72] | per-wave sqp[32][72] | per-wave sO[16][72]
    //            reduce view = per-wave float red[32][68]
    __shared__ __align__(16) char smem[34816];
    __shared__ float scc[32];
    __shared__ __align__(16) float sks[2048];   // ksums slice for batch b
    short* sqin = reinterpret_cast<short*>(smem);                    // [32][72]
    short* sqp  = reinterpret_cast<short*>(smem) + 2304 * (1 + w);   // wave's q' [32][72]
    short* sOw  = reinterpret_cast<short*>(smem) + 2304 * 5 + 1152 * w;  // wave's O [16][72]

    // stage q tile (fp32 -> bf16, s-major): 256 thr x 8 floats = 32x64
    {
        const int row = t >> 3, c8 = (t & 7) * 8;
        const float* qp = query + ((size_t)b * SS + s0 + row) * 64 + c8;
        float4 f0 = *reinterpret_cast<const float4*>(qp);
        float4 f1 = *reinterpret_cast<const float4*>(qp + 4);
        *reinterpret_cast<short8*>(&sqin[row * 72 + c8]) = cvt8(f0, f1);
    }
    // preload this batch's ksums (2048 floats) coalesced
    {
        const float* kb = ksums + (size_t)b * HH * 128;
#pragma unroll
        for (int j = 0; j < 2; ++j) {
            const int o4 = j * 256 + t;     // float4 index, 0..511
            reinterpret_cast<float4*>(sks)[o4] =
                reinterpret_cast<const float4*>(kb)[o4];
        }
    }
    if (t < 32) {
        float p = PI_C * (float)(s0 + t) * (1.f / 4096.f);
        scc[t] = __cosf(p) + __sinf(p);
    }
    f32x4 cd[2][4];
#pragma unroll
    for (int rt = 0; rt < 2; ++rt)
#pragma unroll
        for (int nt = 0; nt < 4; ++nt) cd[rt][nt] = (f32x4){0.f, 0.f, 0.f, 0.f};
    __syncthreads();   // q tile + sks + scc ready (only barrier before epilogue)

    // hoisted head-independent values
    short8 aq[2][2];   // q^T B-frags for the 2 row-tiles
#pragma unroll
    for (int rt = 0; rt < 2; ++rt)
#pragma unroll
        for (int kss = 0; kss < 2; ++kss)
            aq[rt][kss] = *reinterpret_cast<const short8*>(&sqin[(rt * 16 + lane15) * 72 + kss * 32 + q8]);
    const float ccs0 = scc[lane15], ccs1 = scc[16 + lane15];  // cos+sin for s-col
    const int drow = l >> 1, dxh = (l & 1) * 32;              // denominator row / x-half
    const float ccr = scc[drow];

#pragma unroll 2
    for (int i = 0; i < 4; ++i) {
        const int h = (i << 2) | w;
        const size_t bh = (size_t)(b * HH + h);
        const short* wqh = wqTb + (size_t)h * 4096;
        const short* wdh = wdTb + (size_t)h * 4096;
        const short* kv1 = kvb  + bh * 4096;
        const short* kv2 = kvsb + bh * 4096;

        // ---- EARLY: issue ALL of this head's kv + dense frag loads now ----
        short8 kf10[4], kf11[4], kf20[4], kf21[4];
        short8 wdf0[4], wdf1[4];
#pragma unroll
        for (int nt = 0; nt < 4; ++nt) {
            const short* a1 = kv1 + (nt * 16 + lane15) * 64;
            const short* a2 = kv2 + (nt * 16 + lane15) * 64;
            kf10[nt] = *reinterpret_cast<const short8*>(a1 + q8);
            kf11[nt] = *reinterpret_cast<const short8*>(a1 + 32 + q8);
            kf20[nt] = *reinterpret_cast<const short8*>(a2 + q8);
            kf21[nt] = *reinterpret_cast<const short8*>(a2 + 32 + q8);
            wdf0[nt] = *reinterpret_cast<const short8*>(wdh + (nt * 16 + lane15) * 64 + q8);
            wdf1[nt] = *reinterpret_cast<const short8*>(wdh + (nt * 16 + lane15) * 64 + 32 + q8);
        }

        // ---- Q projection, SWAPPED (A=wq^T, B=q^T): lane x=nt*16+q4+r, s=rt*16+lane15 ----
        f32x4 cq[2][4];
#pragma unroll
        for (int rt = 0; rt < 2; ++rt)
#pragma unroll
            for (int nt = 0; nt < 4; ++nt) cq[rt][nt] = (f32x4){0.f, 0.f, 0.f, 0.f};
#pragma unroll
        for (int nt = 0; nt < 4; ++nt) {
            short8 b0 = *reinterpret_cast<const short8*>(wqh + (nt * 16 + lane15) * 64 + q8);
            short8 b1 = *reinterpret_cast<const short8*>(wqh + (nt * 16 + lane15) * 64 + 32 + q8);
            cq[0][nt] = MFMA(b0, aq[0][0], cq[0][nt]);
            cq[1][nt] = MFMA(b0, aq[1][0], cq[1][nt]);
            cq[0][nt] = MFMA(b1, aq[0][1], cq[0][nt]);
            cq[1][nt] = MFMA(b1, aq[1][1], cq[1][nt]);
        }
        // bias + elu, store q' s-major
#pragma unroll
        for (int nt = 0; nt < 4; ++nt) {
            float4 bq = *reinterpret_cast<const float4*>(wq_b + h * 64 + nt * 16 + q4);
#pragma unroll
            for (int rt = 0; rt < 2; ++rt) {
                short e0 = f2bf(elu1(cq[rt][nt][0] + bq.x));
                short e1 = f2bf(elu1(cq[rt][nt][1] + bq.y));
                short e2 = f2bf(elu1(cq[rt][nt][2] + bq.z));
                short e3 = f2bf(elu1(cq[rt][nt][3] + bq.w));
                st4(&sqp[(rt * 16 + lane15) * 72 + nt * 16 + q4], e0, e1, e2, e3);
            }
        }

        // ---- denominator: lane covers row drow, x-half dxh (32 terms; LDS) ----
        float invs0, invs1;
        {
            const float* kp = sks + h * 128 + dxh;
            float4 A[8], Bv[8];
#pragma unroll
            for (int j = 0; j < 8; ++j) {
                A[j]  = *reinterpret_cast<const float4*>(kp + j * 4);
                Bv[j] = *reinterpret_cast<const float4*>(kp + 64 + j * 4);
            }
            short8 qr[4];
#pragma unroll
            for (int e = 0; e < 4; ++e)
                qr[e] = *reinterpret_cast<const short8*>(&sqp[drow * 72 + dxh + e * 8]);
            float dsum = 0.f;
#pragma unroll
            for (int j4 = 0; j4 < 8; ++j4)
#pragma unroll
                for (int e4 = 0; e4 < 4; ++e4)
                    dsum += bf2f(qr[j4 >> 1][(j4 & 1) * 4 + e4]) * (A[j4][e4] + ccr * Bv[j4][e4]);
            dsum += __shfl_xor(dsum, 1);
            float invd = 1.f / (dsum + 1e-5f);
            invs0 = __shfl(invd, lane15 * 2);
            invs1 = __shfl(invd, (16 + lane15) * 2);
        }

        // ---- numerator, SWAPPED (A=kv^T, B=q'^T): frags preloaded above ----
        short8 qf[2][2];
#pragma unroll
        for (int rt = 0; rt < 2; ++rt)
#pragma unroll
            for (int kss = 0; kss < 2; ++kss)
                qf[rt][kss] = *reinterpret_cast<const short8*>(&sqp[(rt * 16 + lane15) * 72 + kss * 32 + q8]);
        f32x4 cv1[2][4], cv2[2][4];
#pragma unroll
        for (int rt = 0; rt < 2; ++rt)
#pragma unroll
            for (int nt = 0; nt < 4; ++nt) {
                cv1[rt][nt] = (f32x4){0.f, 0.f, 0.f, 0.f};
                cv2[rt][nt] = (f32x4){0.f, 0.f, 0.f, 0.f};
            }
#pragma unroll
        for (int nt = 0; nt < 4; ++nt) {
#pragma unroll
            for (int rt = 0; rt < 2; ++rt) {
                cv1[rt][nt] = MFMA(kf10[nt], qf[rt][0], cv1[rt][nt]);
                cv1[rt][nt] = MFMA(kf11[nt], qf[rt][1], cv1[rt][nt]);
                cv2[rt][nt] = MFMA(kf20[nt], qf[rt][0], cv2[rt][nt]);
                cv2[rt][nt] = MFMA(kf21[nt], qf[rt][1], cv2[rt][nt]);
            }
        }

        // ---- per row-tile: combine -> O scratch -> dense GEMM ----
#pragma unroll
        for (int rt = 0; rt < 2; ++rt) {
            const float ccsr = rt ? ccs1 : ccs0;
            const float invr = rt ? invs1 : invs0;
#pragma unroll
            for (int nt = 0; nt < 4; ++nt) {
                short e0 = f2bf((cv1[rt][nt][0] + ccsr * cv2[rt][nt][0]) * invr);
                short e1 = f2bf((cv1[rt][nt][1] + ccsr * cv2[rt][nt][1]) * invr);
                short e2 = f2bf((cv1[rt][nt][2] + ccsr * cv2[rt][nt][2]) * invr);
                short e3 = f2bf((cv1[rt][nt][3] + ccsr * cv2[rt][nt][3]) * invr);
                st4(&sOw[lane15 * 72 + nt * 16 + q4], e0, e1, e2, e3);
            }
            short8 of0 = *reinterpret_cast<const short8*>(&sOw[lane15 * 72 + q8]);
            short8 of1 = *reinterpret_cast<const short8*>(&sOw[lane15 * 72 + 32 + q8]);
#pragma unroll
            for (int nt = 0; nt < 4; ++nt) {
                cd[rt][nt] = MFMA(of0, wdf0[nt], cd[rt][nt]);
                cd[rt][nt] = MFMA(of1, wdf1[nt], cd[rt][nt]);
            }
        }
    }

    // ---- cross-wave reduction of dense partials (re-alias LDS union) ----
    __syncthreads();   // all compute reads of smem done
    {
        float* red = reinterpret_cast<float*>(smem) + 2176 * w;   // [32][68]
#pragma unroll
        for (int rt = 0; rt < 2; ++rt)
#pragma unroll
            for (int nt = 0; nt < 4; ++nt)
#pragma unroll
                for (int r = 0; r < 4; ++r)
                    red[(rt * 16 + q4 + r) * 68 + nt * 16 + lane15] = cd[rt][nt][r];
    }
    __syncthreads();
    {
        const int row = t >> 3, c8 = (t & 7) * 8;
        float4 sa = make_float4(0.f, 0.f, 0.f, 0.f);
        float4 sb = make_float4(0.f, 0.f, 0.f, 0.f);
#pragma unroll
        for (int ww = 0; ww < 4; ++ww) {
            const float* red = reinterpret_cast<const float*>(smem) + 2176 * ww;
            float4 v0 = *reinterpret_cast<const float4*>(red + row * 68 + c8);
            float4 v1 = *reinterpret_cast<const float4*>(red + row * 68 + c8 + 4);
            sa.x += v0.x; sa.y += v0.y; sa.z += v0.z; sa.w += v0.w;
            sb.x += v1.x; sb.y += v1.y; sb.z += v1.z; sb.w += v1.w;
        }
        float4 d0 = *reinterpret_cast<const float4*>(dense_b + c8);
        float4 d1 = *reinterpret_cast<const float4*>(dense_b + c8 + 4);
        sa.x += d0.x; sa.y += d0.y; sa.z += d0.z; sa.w += d0.w;
        sb.x += d1.x; sb.y += d1.y; sb.z += d1.z; sb.w += d1.w;
        float* op = out + ((size_t)b * SS + s0 + row) * 64 + c8;
        *reinterpret_cast<float4*>(op)     = sa;
        *reinterpret_cast<float4*>(op + 4) = sb;
    }
}

// ---------------------------------------------------------------------------
extern "C" void kernel_launch(void* const* d_in, const int* in_sizes, int n_in,
                              void* d_out, int out_size, void* d_ws, size_t ws_size,
                              hipStream_t stream) {
    const float* query   = (const float*)d_in[0];
    const float* key     = (const float*)d_in[1];
    const float* value   = (const float*)d_in[2];
    // d_in[3] attn_mask unused
    const float* wq_w    = (const float*)d_in[4];
    const float* wq_b    = (const float*)d_in[5];
    const float* wk_w    = (const float*)d_in[6];
    const float* wk_b    = (const float*)d_in[7];
    const float* wv_w    = (const float*)d_in[8];
    const float* wv_b    = (const float*)d_in[9];
    const float* dense_w = (const float*)d_in[10];
    const float* dense_b = (const float*)d_in[11];
    float* out = (float*)d_out;

    char* ws = (char*)d_ws;
    float* pkv   = (float*)(ws);
    float* pkvs  = (float*)(ws + 8388608);
    float* pks   = (float*)(ws + 16777216);
    short* kvb   = (short*)(ws + 17039360);
    short* kvsb  = (short*)(ws + 17563648);
    float* ksums = (float*)(ws + 18087936);
    short* wT    = (short*)(ws + 18120704);  // wq|wk|wv|wd, 65536 shorts each
    short* wqTb  = wT;
    short* wdTb  = wT + 196608;

    hipLaunchKernelGGL(k_phase1y, dim3(544), dim3(256), 0, stream,
                       key, value, wk_b, wv_b, wk_w, wv_w, wq_w, dense_w,
                       pkv, pkvs, pks, wT);
    hipLaunchKernelGGL(k_reduce, dim3(520), dim3(256), 0, stream,
                       pkv, pkvs, pks, kvb, kvsb, ksums);
    hipLaunchKernelGGL(k_phase2, dim3(128, BB), dim3(256), 0, stream,
                       query, wq_b, wqTb, kvb, kvsb, ksums, wdTb, dense_b, out);
}

// Round 14
// 138.339 us; speedup vs baseline: 1.0410x; 1.0262x over previous
//
#include <hip/hip_runtime.h>
#include <math.h>

// Problem constants
#define BB 4
#define SS 4096
#define DD 64
#define HH 16
#define PI_C 3.1415f

// ---------------------------------------------------------------------------
// ws layout (bytes):
//   0        : pkv   fp32 [8][64bh][z*64+x]   8,388,608
//   8388608  : pkvs  fp32 [8][64bh][z*64+x]   8,388,608
//   16777216 : pks   fp32 [8][64bh][128]        262,144   (ksum|kssum)
//   17039360 : kvb   bf16 [64bh][z*64+x]        524,288
//   17563648 : kvsb  bf16                       524,288
//   18087936 : ksums fp32 [64bh][128]            32,768
//   18120704 : wT    bf16 wq|wk|wv|wd x 65536   524,288  (only wq,wd written)
// ---------------------------------------------------------------------------

typedef __attribute__((ext_vector_type(8))) short short8;   // 8 x bf16 frag
typedef __attribute__((ext_vector_type(4))) float f32x4;    // MFMA C/D frag

#define MFMA(a, b, c) __builtin_amdgcn_mfma_f32_16x16x32_bf16(a, b, c, 0, 0, 0)

__device__ __forceinline__ short f2bf(float f) {
    union { float f; unsigned u; } v; v.f = f;
    unsigned r = v.u + 0x7FFFu + ((v.u >> 16) & 1u);   // round-to-nearest-even
    return (short)(r >> 16);
}
__device__ __forceinline__ float bf2f(short s) {
    union { unsigned u; float f; } v;
    v.u = ((unsigned)(unsigned short)s) << 16;
    return v.f;
}
__device__ __forceinline__ short8 cvt8(float4 a, float4 b) {
    short8 r;
    r[0] = f2bf(a.x); r[1] = f2bf(a.y); r[2] = f2bf(a.z); r[3] = f2bf(a.w);
    r[4] = f2bf(b.x); r[5] = f2bf(b.y); r[6] = f2bf(b.z); r[7] = f2bf(b.w);
    return r;
}
__device__ __forceinline__ float elu1(float x) { return x > 0.f ? x + 1.f : __expf(x); }
__device__ __forceinline__ void st4(short* p, short a, short b, short c, short d) {
    union { uint2 u; short s[4]; } x;
    x.s[0] = a; x.s[1] = b; x.s[2] = c; x.s[3] = d;
    *reinterpret_cast<uint2*>(p) = x.u;
}

// ---------------------------------------------------------------------------
// Phase 1 (prep-fused, R11-exact): blocks 0..511 = R2 phase1 body with
// SELF-TRANSPOSED wk/wv; blocks 512..543 = prep riders for wq / dense_w.
__global__ __launch_bounds__(256, 2) void k_phase1y(
    const float* __restrict__ key, const float* __restrict__ value,
    const float* __restrict__ wk_b, const float* __restrict__ wv_b,
    const float* __restrict__ wk_w, const float* __restrict__ wv_w,
    const float* __restrict__ wq_w, const float* __restrict__ wd_w,
    float* __restrict__ pkv, float* __restrict__ pkvs,
    float* __restrict__ pks,
    short* __restrict__ wT)
{
    const int blk = blockIdx.x, t = threadIdx.x;

    __shared__ short kT[2][64 * 72], vT[2][64 * 72], vsT[2][64 * 72];   // [buf][x|z][s]
    __shared__ float ssin[512];
    __shared__ float sbk[64], sbv[64];
    __shared__ float sred[512];

    // ---- prep rider blocks: transpose wq (pb<16) / dense_w (pb>=16) ----
    if (blk >= 512) {
        const int pb = blk - 512;
        const int h = pb & 15;
        const bool isQ = (pb < 16);
        const float* src = isQ ? wq_w : wd_w;
        const int rs = isQ ? 1024 : 64;
        const size_t srcbase = isQ ? (size_t)(h * 64) : (size_t)(h * 4096);
        short* dm = wT + (isQ ? (size_t)0 : (size_t)3 * 65536) + (size_t)h * 4096;
#pragma unroll
        for (int j = 0; j < 4; ++j) {
            int idx = j * 1024 + t * 4;
            int r = idx >> 6, c = idx & 63;
            float4 v = *reinterpret_cast<const float4*>(src + (size_t)r * rs + srcbase + c);
            dm[(c + 0) * 64 + r] = f2bf(v.x);
            dm[(c + 1) * 64 + r] = f2bf(v.y);
            dm[(c + 2) * 64 + r] = f2bf(v.z);
            dm[(c + 3) * 64 + r] = f2bf(v.w);
        }
        return;
    }

    const int chunk = blk & 7, h = (blk >> 3) & 15, b = blk >> 7;
    const int w = t >> 6, l = t & 63;
    const int lane15 = l & 15, q8 = (l >> 4) * 8, q4 = (l >> 4) * 4;

    // prefetch K/V rows for iter 0 (independent of LDS; issue first)
    float4 kf0, kf1, kf2, kf3, vf0, vf1, vf2, vf3;
    {
        const size_t g = ((size_t)b * SS + chunk * 512 + w * 16 + lane15) * 64 + q8;
        kf0 = *reinterpret_cast<const float4*>(key + g);
        kf1 = *reinterpret_cast<const float4*>(key + g + 4);
        kf2 = *reinterpret_cast<const float4*>(key + g + 32);
        kf3 = *reinterpret_cast<const float4*>(key + g + 36);
        vf0 = *reinterpret_cast<const float4*>(value + g);
        vf1 = *reinterpret_cast<const float4*>(value + g + 4);
        vf2 = *reinterpret_cast<const float4*>(value + g + 32);
        vf3 = *reinterpret_cast<const float4*>(value + g + 36);
    }

    // ---- self-transpose wk/wv head h into LDS (aliases kT double-buffer) ----
    short* wkL = &kT[0][0];   // [64][72]
    short* wvL = &kT[1][0];   // [64][72]
    {
        const int r = t >> 2, c0 = (t & 3) * 16;
        const float* pkw = wk_w + (size_t)r * 1024 + h * 64 + c0;
        const float* pvw = wv_w + (size_t)r * 1024 + h * 64 + c0;
#pragma unroll
        for (int q = 0; q < 4; ++q) {
            float4 a = *reinterpret_cast<const float4*>(pkw + q * 4);
            float4 v = *reinterpret_cast<const float4*>(pvw + q * 4);
            wkL[(c0 + q * 4 + 0) * 72 + r] = f2bf(a.x);
            wkL[(c0 + q * 4 + 1) * 72 + r] = f2bf(a.y);
            wkL[(c0 + q * 4 + 2) * 72 + r] = f2bf(a.z);
            wkL[(c0 + q * 4 + 3) * 72 + r] = f2bf(a.w);
            wvL[(c0 + q * 4 + 0) * 72 + r] = f2bf(v.x);
            wvL[(c0 + q * 4 + 1) * 72 + r] = f2bf(v.y);
            wvL[(c0 + q * 4 + 2) * 72 + r] = f2bf(v.z);
            wvL[(c0 + q * 4 + 3) * 72 + r] = f2bf(v.w);
        }
    }
    ssin[t]       = __sinf(PI_C * (float)(chunk * 512 + t)       * (1.f / 4096.f));
    ssin[t + 256] = __sinf(PI_C * (float)(chunk * 512 + t + 256) * (1.f / 4096.f));
    if (t < 64) sbk[t] = wk_b[h * 64 + t];
    else if (t < 128) sbv[t - 64] = wv_b[h * 64 + (t - 64)];
    __syncthreads();   // staged weights + ssin/sbk/sbv visible

    // weight B-frags -> registers (bit-identical to prep-based path)
    short8 bkf[2][4], bvf[2][4];
#pragma unroll
    for (int kss = 0; kss < 2; ++kss)
#pragma unroll
        for (int nt = 0; nt < 4; ++nt) {
            bkf[kss][nt] = *reinterpret_cast<const short8*>(&wkL[(nt * 16 + lane15) * 72 + kss * 32 + q8]);
            bvf[kss][nt] = *reinterpret_cast<const short8*>(&wvL[(nt * 16 + lane15) * 72 + kss * 32 + q8]);
        }
    __syncthreads();   // frags read; kT area free for proj_store

    f32x4 ckv[4], ckvs[4];
#pragma unroll
    for (int i = 0; i < 4; ++i) {
        ckv[i]  = (f32x4){0.f, 0.f, 0.f, 0.f};
        ckvs[i] = (f32x4){0.f, 0.f, 0.f, 0.f};
    }
    float aks = 0.f, akss = 0.f;

    // projection + bias + act + transposed bf16 stores into buffer `buf`
    auto proj_store = [&](int buf, int sbase) {
        f32x4 ckp[4], cvp[4];
#pragma unroll
        for (int i = 0; i < 4; ++i) {
            ckp[i] = (f32x4){0.f, 0.f, 0.f, 0.f};
            cvp[i] = (f32x4){0.f, 0.f, 0.f, 0.f};
        }
        short8 ak0 = cvt8(kf0, kf1), ak1 = cvt8(kf2, kf3);
        short8 av0 = cvt8(vf0, vf1), av1 = cvt8(vf2, vf3);
#pragma unroll
        for (int nt = 0; nt < 4; ++nt) {
            ckp[nt] = MFMA(ak0, bkf[0][nt], ckp[nt]);
            cvp[nt] = MFMA(av0, bvf[0][nt], cvp[nt]);
            ckp[nt] = MFMA(ak1, bkf[1][nt], ckp[nt]);
            cvp[nt] = MFMA(av1, bvf[1][nt], cvp[nt]);
        }
        const int srel = w * 16 + q4;
#pragma unroll
        for (int nt = 0; nt < 4; ++nt) {
            const int x = nt * 16 + lane15;
            const float bk = sbk[x], bv = sbv[x];
            short ek[4], ev[4], es[4];
#pragma unroll
            for (int r = 0; r < 4; ++r) {
                float kk = elu1(ckp[nt][r] + bk);
                float vv = cvp[nt][r] + bv;
                ek[r] = f2bf(kk);
                ev[r] = f2bf(vv);
                es[r] = f2bf(vv * ssin[sbase + srel + r]);
            }
            st4(&kT [buf][x * 72 + srel], ek[0], ek[1], ek[2], ek[3]);
            st4(&vT [buf][x * 72 + srel], ev[0], ev[1], ev[2], ev[3]);
            st4(&vsT[buf][x * 72 + srel], es[0], es[1], es[2], es[3]);
        }
    };

    proj_store(0, 0);          // peeled: tile 0 -> buffer 0
    __syncthreads();           // buffer 0 complete

#pragma unroll 1
    for (int it = 0; it < 8; ++it) {
        const int cur = it & 1;
        // ---- prefetch next tile's K/V rows (global; overlaps everything) ----
        if (it < 7) {
            const size_t g = ((size_t)b * SS + chunk * 512 + (it + 1) * 64 + w * 16 + lane15) * 64 + q8;
            kf0 = *reinterpret_cast<const float4*>(key + g);
            kf1 = *reinterpret_cast<const float4*>(key + g + 4);
            kf2 = *reinterpret_cast<const float4*>(key + g + 32);
            kf3 = *reinterpret_cast<const float4*>(key + g + 36);
            vf0 = *reinterpret_cast<const float4*>(value + g);
            vf1 = *reinterpret_cast<const float4*>(value + g + 4);
            vf2 = *reinterpret_cast<const float4*>(value + g + 32);
            vf3 = *reinterpret_cast<const float4*>(value + g + 36);
        }
        // ---- kv / kvs GEMM from buffer cur, swapped: A=v (m=z), B=k' (n=x) ----
#pragma unroll
        for (int kstep = 0; kstep < 2; ++kstep) {
            const int so = kstep * 32;
            short8 aV  = *reinterpret_cast<const short8*>(&vT [cur][(w * 16 + lane15) * 72 + so + q8]);
            short8 aVS = *reinterpret_cast<const short8*>(&vsT[cur][(w * 16 + lane15) * 72 + so + q8]);
#pragma unroll
            for (int nt = 0; nt < 4; ++nt) {
                short8 bK = *reinterpret_cast<const short8*>(&kT[cur][(nt * 16 + lane15) * 72 + so + q8]);
                ckv[nt]  = MFMA(aV,  bK, ckv[nt]);
                ckvs[nt] = MFMA(aVS, bK, ckvs[nt]);
            }
        }
        // ---- ksum / kssum partials (thread: x = l, s-range [w*16,+16)) ----
        {
            const int sbase = it * 64;
            short8 k0 = *reinterpret_cast<const short8*>(&kT[cur][l * 72 + w * 16]);
            short8 k1 = *reinterpret_cast<const short8*>(&kT[cur][l * 72 + w * 16 + 8]);
#pragma unroll
            for (int e = 0; e < 8; ++e) {
                float fa = bf2f(k0[e]), fb = bf2f(k1[e]);
                aks  += fa + fb;
                akss += fa * ssin[sbase + w * 16 + e] + fb * ssin[sbase + w * 16 + 8 + e];
            }
        }
        // ---- project tile it+1 into the other buffer (same interval) ----
        if (it < 7) proj_store(cur ^ 1, (it + 1) * 64);
        __syncthreads();
    }

    // ---- commit: coalesced non-atomic partial stores ([z][x], x = lane15) ----
    const int bh = b * HH + h;
    const size_t pbase = ((size_t)(chunk * 64) + bh) * 4096;
#pragma unroll
    for (int nt = 0; nt < 4; ++nt) {
        const int x = nt * 16 + lane15;
#pragma unroll
        for (int r = 0; r < 4; ++r) {
            const int z = w * 16 + q4 + r;
            pkv [pbase + z * 64 + x] = ckv[nt][r];
            pkvs[pbase + z * 64 + x] = ckvs[nt][r];
        }
    }
    sred[t] = aks; sred[256 + t] = akss;
    __syncthreads();
    if (t < 64) {
        pks[((size_t)(chunk * 64) + bh) * 128 + t] =
            sred[t] + sred[64 + t] + sred[128 + t] + sred[192 + t];
    } else if (t < 128) {
        int tt = t - 64;
        pks[((size_t)(chunk * 64) + bh) * 128 + t] =
            sred[256 + tt] + sred[320 + tt] + sred[384 + tt] + sred[448 + tt];
    }
}

// ---------------------------------------------------------------------------
// Reduce 8 chunk partials -> bf16 kv/kvs + fp32 ksums (R2-exact).
__global__ __launch_bounds__(256) void k_reduce(
    const float* __restrict__ pkv, const float* __restrict__ pkvs,
    const float* __restrict__ pks,
    short* __restrict__ kvb, short* __restrict__ kvsb,
    float* __restrict__ ksums)
{
    const int blk = blockIdx.x, t = threadIdx.x;
    if (blk < 512) {
        const float* src = (blk < 256) ? pkv : pkvs;
        short* dst = (blk < 256) ? kvb : kvsb;
        const int o4 = (blk & 255) * 256 + t;          // float4 index, 0..65535
        float4 s = make_float4(0.f, 0.f, 0.f, 0.f);
#pragma unroll
        for (int c = 0; c < 8; ++c) {
            float4 v = reinterpret_cast<const float4*>(src + (size_t)c * 262144)[o4];
            s.x += v.x; s.y += v.y; s.z += v.z; s.w += v.w;
        }
        st4(dst + (size_t)o4 * 4, f2bf(s.x), f2bf(s.y), f2bf(s.z), f2bf(s.w));
    } else {
        const int g = (blk - 512) * 256 + t;           // float4 index, 0..2047
        float4 s = make_float4(0.f, 0.f, 0.f, 0.f);
#pragma unroll
        for (int c = 0; c < 8; ++c) {
            float4 v = reinterpret_cast<const float4*>(pks + (size_t)c * 8192)[g];
            s.x += v.x; s.y += v.y; s.z += v.z; s.w += v.w;
        }
        reinterpret_cast<float4*>(ksums)[g] = s;
    }
}

// ---------------------------------------------------------------------------
// Phase 2 (64-row tiles, 8-wave blocks, grid 64x4 = 1 block/CU = same 2
// waves/SIMD as before): wave w owns heads {w, 8+w}; per head, kv frags are
// loaded ONCE and reused across two 32-row halves (frag loads per row 4x
// lower). q'/O share the per-wave scratch (R4-validated). Dense partials in
// cd[half][rt][nt] regs; row-half-staged 8->4->1 LDS reduction epilogue.
// launch_bounds(512,2) caps 256 regs (est. peak ~220, no spill).
__global__ __launch_bounds__(512, 2) void k_phase2(
    const float* __restrict__ query, const float* __restrict__ wq_b,
    const short* __restrict__ wqTb,
    const short* __restrict__ kvb, const short* __restrict__ kvsb,
    const float* __restrict__ ksums,
    const short* __restrict__ wdTb, const float* __restrict__ dense_b,
    float* __restrict__ out)
{
    const int st = blockIdx.x, b = blockIdx.y;
    const int s0 = st * 64;
    const int t = threadIdx.x, w = t >> 6, l = t & 63;
    const int lane15 = l & 15, q8 = (l >> 4) * 8, q4 = (l >> 4) * 4;

    // LDS arena: sqin[64][72] (9216B) + 8 x per-wave sqp[32][72] (4608B each).
    // Epilogue re-aliases the arena as 4 x float[32][68] (34816B <= 46080B).
    __shared__ __align__(16) char smem[46080];
    __shared__ float scc[64];
    __shared__ __align__(16) float sks[2048];   // ksums slice for batch b
    short* sqin = reinterpret_cast<short*>(smem);                    // [64][72]
    short* sqp  = reinterpret_cast<short*>(smem) + 4608 + 2304 * w;  // wave scratch [32][72]

    // stage q tile (fp32 -> bf16, s-major): 512 thr x 8 floats = 64x64
    {
        const int row = t >> 3, c8 = (t & 7) * 8;
        const float* qp = query + ((size_t)b * SS + s0 + row) * 64 + c8;
        float4 f0 = *reinterpret_cast<const float4*>(qp);
        float4 f1 = *reinterpret_cast<const float4*>(qp + 4);
        *reinterpret_cast<short8*>(&sqin[row * 72 + c8]) = cvt8(f0, f1);
    }
    // preload this batch's ksums (2048 floats): one float4 per thread
    {
        const float* kb = ksums + (size_t)b * HH * 128;
        reinterpret_cast<float4*>(sks)[t] = reinterpret_cast<const float4*>(kb)[t];
    }
    if (t < 64) {
        float p = PI_C * (float)(s0 + t) * (1.f / 4096.f);
        scc[t] = __cosf(p) + __sinf(p);
    }
    f32x4 cd[2][2][4];   // [half][rt][nt]
#pragma unroll
    for (int hf = 0; hf < 2; ++hf)
#pragma unroll
        for (int rt = 0; rt < 2; ++rt)
#pragma unroll
            for (int nt = 0; nt < 4; ++nt) cd[hf][rt][nt] = (f32x4){0.f, 0.f, 0.f, 0.f};
    __syncthreads();   // q tile + sks + scc ready

    const int drow = l >> 1, dxh = (l & 1) * 32;   // denominator row (in-half) / x-half

#pragma unroll 1
    for (int hi = 0; hi < 2; ++hi) {
        const int h = hi * 8 + w;
        const size_t bh = (size_t)(b * HH + h);
        const short* wqh = wqTb + (size_t)h * 4096;
        const short* wdh = wdTb + (size_t)h * 4096;
        const short* kv1 = kvb  + bh * 4096;
        const short* kv2 = kvsb + bh * 4096;

        // ---- kv frags loaded ONCE per head, reused across both halves ----
        short8 kf10[4], kf11[4], kf20[4], kf21[4];
#pragma unroll
        for (int nt = 0; nt < 4; ++nt) {
            const short* a1 = kv1 + (nt * 16 + lane15) * 64;
            const short* a2 = kv2 + (nt * 16 + lane15) * 64;
            kf10[nt] = *reinterpret_cast<const short8*>(a1 + q8);
            kf11[nt] = *reinterpret_cast<const short8*>(a1 + 32 + q8);
            kf20[nt] = *reinterpret_cast<const short8*>(a2 + q8);
            kf21[nt] = *reinterpret_cast<const short8*>(a2 + 32 + q8);
        }

#pragma unroll
        for (int hf = 0; hf < 2; ++hf) {
            const int rbase = hf * 32;   // absolute row base of this half

            // ---- Q projection, SWAPPED: lane x=nt*16+q4+r, s=rbase+rt*16+lane15 ----
            short8 aq0[2], aq1[2];
#pragma unroll
            for (int rt = 0; rt < 2; ++rt) {
                aq0[rt] = *reinterpret_cast<const short8*>(&sqin[(rbase + rt * 16 + lane15) * 72 + q8]);
                aq1[rt] = *reinterpret_cast<const short8*>(&sqin[(rbase + rt * 16 + lane15) * 72 + 32 + q8]);
            }
            f32x4 cq[2][4];
#pragma unroll
            for (int rt = 0; rt < 2; ++rt)
#pragma unroll
                for (int nt = 0; nt < 4; ++nt) cq[rt][nt] = (f32x4){0.f, 0.f, 0.f, 0.f};
#pragma unroll
            for (int nt = 0; nt < 4; ++nt) {
                short8 b0 = *reinterpret_cast<const short8*>(wqh + (nt * 16 + lane15) * 64 + q8);
                short8 b1 = *reinterpret_cast<const short8*>(wqh + (nt * 16 + lane15) * 64 + 32 + q8);
                cq[0][nt] = MFMA(b0, aq0[0], cq[0][nt]);
                cq[1][nt] = MFMA(b0, aq0[1], cq[1][nt]);
                cq[0][nt] = MFMA(b1, aq1[0], cq[0][nt]);
                cq[1][nt] = MFMA(b1, aq1[1], cq[1][nt]);
            }
            // bias + elu, store q' s-major (rows 0..31 of wave scratch)
#pragma unroll
            for (int nt = 0; nt < 4; ++nt) {
                float4 bq = *reinterpret_cast<const float4*>(wq_b + h * 64 + nt * 16 + q4);
#pragma unroll
                for (int rt = 0; rt < 2; ++rt) {
                    short e0 = f2bf(elu1(cq[rt][nt][0] + bq.x));
                    short e1 = f2bf(elu1(cq[rt][nt][1] + bq.y));
                    short e2 = f2bf(elu1(cq[rt][nt][2] + bq.z));
                    short e3 = f2bf(elu1(cq[rt][nt][3] + bq.w));
                    st4(&sqp[(rt * 16 + lane15) * 72 + nt * 16 + q4], e0, e1, e2, e3);
                }
            }

            // ---- denominator (rows rbase+drow; 32 terms/lane + pair reduce) ----
            float invs0, invs1;
            {
                const float ccr = scc[rbase + drow];
                const float* kp = sks + h * 128 + dxh;
                float4 A[8], Bv[8];
#pragma unroll
                for (int j = 0; j < 8; ++j) {
                    A[j]  = *reinterpret_cast<const float4*>(kp + j * 4);
                    Bv[j] = *reinterpret_cast<const float4*>(kp + 64 + j * 4);
                }
                short8 qr[4];
#pragma unroll
                for (int e = 0; e < 4; ++e)
                    qr[e] = *reinterpret_cast<const short8*>(&sqp[drow * 72 + dxh + e * 8]);
                float dsum = 0.f;
#pragma unroll
                for (int j4 = 0; j4 < 8; ++j4)
#pragma unroll
                    for (int e4 = 0; e4 < 4; ++e4)
                        dsum += bf2f(qr[j4 >> 1][(j4 & 1) * 4 + e4]) * (A[j4][e4] + ccr * Bv[j4][e4]);
                dsum += __shfl_xor(dsum, 1);
                float invd = 1.f / (dsum + 1e-5f);
                invs0 = __shfl(invd, lane15 * 2);
                invs1 = __shfl(invd, (16 + lane15) * 2);
            }

            // ---- numerator (kv frags reused): z=nt*16+q4+r, s=rbase+rt*16+lane15 ----
            short8 qf[2][2];
#pragma unroll
            for (int rt = 0; rt < 2; ++rt)
#pragma unroll
                for (int kss = 0; kss < 2; ++kss)
                    qf[rt][kss] = *reinterpret_cast<const short8*>(&sqp[(rt * 16 + lane15) * 72 + kss * 32 + q8]);
            f32x4 cv1[2][4], cv2[2][4];
#pragma unroll
            for (int rt = 0; rt < 2; ++rt)
#pragma unroll
                for (int nt = 0; nt < 4; ++nt) {
                    cv1[rt][nt] = (f32x4){0.f, 0.f, 0.f, 0.f};
                    cv2[rt][nt] = (f32x4){0.f, 0.f, 0.f, 0.f};
                }
#pragma unroll
            for (int nt = 0; nt < 4; ++nt) {
#pragma unroll
                for (int rt = 0; rt < 2; ++rt) {
                    cv1[rt][nt] = MFMA(kf10[nt], qf[rt][0], cv1[rt][nt]);
                    cv1[rt][nt] = MFMA(kf11[nt], qf[rt][1], cv1[rt][nt]);
                    cv2[rt][nt] = MFMA(kf20[nt], qf[rt][0], cv2[rt][nt]);
                    cv2[rt][nt] = MFMA(kf21[nt], qf[rt][1], cv2[rt][nt]);
                }
            }

            // ---- combine -> O over q' scratch (q' dead; R4-validated) -> dense ----
            const float ccs0 = scc[rbase + lane15], ccs1 = scc[rbase + 16 + lane15];
#pragma unroll
            for (int rt = 0; rt < 2; ++rt) {
                const float ccsr = rt ? ccs1 : ccs0;
                const float invr = rt ? invs1 : invs0;
#pragma unroll
                for (int nt = 0; nt < 4; ++nt) {
                    short e0 = f2bf((cv1[rt][nt][0] + ccsr * cv2[rt][nt][0]) * invr);
                    short e1 = f2bf((cv1[rt][nt][1] + ccsr * cv2[rt][nt][1]) * invr);
                    short e2 = f2bf((cv1[rt][nt][2] + ccsr * cv2[rt][nt][2]) * invr);
                    short e3 = f2bf((cv1[rt][nt][3] + ccsr * cv2[rt][nt][3]) * invr);
                    st4(&sqp[(rt * 16 + lane15) * 72 + nt * 16 + q4], e0, e1, e2, e3);
                }
                short8 of0 = *reinterpret_cast<const short8*>(&sqp[(rt * 16 + lane15) * 72 + q8]);
                short8 of1 = *reinterpret_cast<const short8*>(&sqp[(rt * 16 + lane15) * 72 + 32 + q8]);
#pragma unroll
                for (int nt = 0; nt < 4; ++nt) {
                    short8 wd0 = *reinterpret_cast<const short8*>(wdh + (nt * 16 + lane15) * 64 + q8);
                    short8 wd1 = *reinterpret_cast<const short8*>(wdh + (nt * 16 + lane15) * 64 + 32 + q8);
                    cd[hf][rt][nt] = MFMA(of0, wd0, cd[hf][rt][nt]);
                    cd[hf][rt][nt] = MFMA(of1, wd1, cd[hf][rt][nt]);
                }
            }
        }
    }

    // ---- epilogue: per row-half, 8->4->1 cross-wave dense reduction ----
#pragma unroll 1
    for (int hf = 0; hf < 2; ++hf) {
        __syncthreads();   // previous users of the arena done
        float* red = reinterpret_cast<float*>(smem) + 2176 * (w & 3);   // [32][68]
        if (w < 4) {
#pragma unroll
            for (int rt = 0; rt < 2; ++rt)
#pragma unroll
                for (int nt = 0; nt < 4; ++nt)
#pragma unroll
                    for (int r = 0; r < 4; ++r)
                        red[(rt * 16 + q4 + r) * 68 + nt * 16 + lane15] =
                            (hf == 0) ? cd[0][rt][nt][r] : cd[1][rt][nt][r];
        }
        __syncthreads();
        if (w >= 4) {
#pragma unroll
            for (int rt = 0; rt < 2; ++rt)
#pragma unroll
                for (int nt = 0; nt < 4; ++nt)
#pragma unroll
                    for (int r = 0; r < 4; ++r)
                        red[(rt * 16 + q4 + r) * 68 + nt * 16 + lane15] +=
                            (hf == 0) ? cd[0][rt][nt][r] : cd[1][rt][nt][r];
        }
        __syncthreads();
        {
            const int row = t >> 4, c4 = (t & 15) * 4;   // 32 rows x 64 cols
            float4 s = make_float4(0.f, 0.f, 0.f, 0.f);
#pragma unroll
            for (int ww = 0; ww < 4; ++ww) {
                const float* rb = reinterpret_cast<const float*>(smem) + 2176 * ww;
                float4 v = *reinterpret_cast<const float4*>(rb + row * 68 + c4);
                s.x += v.x; s.y += v.y; s.z += v.z; s.w += v.w;
            }
            float4 db = *reinterpret_cast<const float4*>(dense_b + c4);
            s.x += db.x; s.y += db.y; s.z += db.z; s.w += db.w;
            *reinterpret_cast<float4*>(
                out + ((size_t)b * SS + s0 + hf * 32 + row) * 64 + c4) = s;
        }
    }
}

// ---------------------------------------------------------------------------
extern "C" void kernel_launch(void* const* d_in, const int* in_sizes, int n_in,
                              void* d_out, int out_size, void* d_ws, size_t ws_size,
                              hipStream_t stream) {
    const float* query   = (const float*)d_in[0];
    const float* key     = (const float*)d_in[1];
    const float* value   = (const float*)d_in[2];
    // d_in[3] attn_mask unused
    const float* wq_w    = (const float*)d_in[4];
    const float* wq_b    = (const float*)d_in[5];
    const float* wk_w    = (const float*)d_in[6];
    const float* wk_b    = (const float*)d_in[7];
    const float* wv_w    = (const float*)d_in[8];
    const float* wv_b    = (const float*)d_in[9];
    const float* dense_w = (const float*)d_in[10];
    const float* dense_b = (const float*)d_in[11];
    float* out = (float*)d_out;

    char* ws = (char*)d_ws;
    float* pkv   = (float*)(ws);
    float* pkvs  = (float*)(ws + 8388608);
    float* pks   = (float*)(ws + 16777216);
    short* kvb   = (short*)(ws + 17039360);
    short* kvsb  = (short*)(ws + 17563648);
    float* ksums = (float*)(ws + 18087936);
    short* wT    = (short*)(ws + 18120704);  // wq|wk|wv|wd, 65536 shorts each
    short* wqTb  = wT;
    short* wdTb  = wT + 196608;

    hipLaunchKernelGGL(k_phase1y, dim3(544), dim3(256), 0, stream,
                       key, value, wk_b, wv_b, wk_w, wv_w, wq_w, dense_w,
                       pkv, pkvs, pks, wT);
    hipLaunchKernelGGL(k_reduce, dim3(520), dim3(256), 0, stream,
                       pkv, pkvs, pks, kvb, kvsb, ksums);
    hipLaunchKernelGGL(k_phase2, dim3(64, BB), dim3(512), 0, stream,
                       query, wq_b, wqTb, kvb, kvsb, ksums, wdTb, dense_b, out);
}